// Round 2
// baseline (114.748 us; speedup 1.0000x reference)
//
#include <hip/hip_runtime.h>

#define NN 512
#define DD 128
#define HH 256
#define OO 256
#define JS 4
#define JCH 128

__device__ __forceinline__ float dot4(float4 a, float4 b) {
    return a.x * b.x + a.y * b.y + a.z * b.z + a.w * b.w;
}

// pa/pb: 256 blocks (128 i-tiles x 2 h-halves), 256 threads.
// Each thread: one h, two rows (rp, rp+1), accA/accB for each -> 4 acc chains.
__global__ __launch_bounds__(256) void k_papb(const float* __restrict__ x,
                                              const float* __restrict__ W1,
                                              float* __restrict__ pa,
                                              float* __restrict__ pb) {
    __shared__ float xs[4][DD];
    const int i0 = blockIdx.x * 4;
    const int h0 = blockIdx.y * (HH / 2);
    const int t = threadIdx.x;
    {
        int idx = t;
        ((float*)xs)[idx] = x[i0 * DD + idx];
        idx = t + 256;
        ((float*)xs)[idx] = x[i0 * DD + idx];
    }
    __syncthreads();
    const int hl = t & 127;
    const int h = h0 + hl;
    const int rp = (t >> 7) * 2;
    const float4* wa = (const float4*)(W1 + h * (2 * DD));
    const float4* wb = wa + (DD / 4);
    const float4* x0 = (const float4*)&xs[rp][0];
    const float4* x1 = (const float4*)&xs[rp + 1][0];
    float a0 = 0.f, a1 = 0.f, b0 = 0.f, b1 = 0.f;
    #pragma unroll 8
    for (int d4 = 0; d4 < DD / 4; ++d4) {
        float4 w_a = wa[d4];
        float4 w_b = wb[d4];
        float4 v0 = x0[d4];
        float4 v1 = x1[d4];
        a0 += dot4(w_a, v0);
        a1 += dot4(w_a, v1);
        b0 += dot4(w_b, v0);
        b1 += dot4(w_b, v1);
    }
    pa[(i0 + rp) * HH + h] = a0;
    pa[(i0 + rp + 1) * HH + h] = a1;
    pb[(i0 + rp) * HH + h] = b0;
    pb[(i0 + rp + 1) * HH + h] = b1;
}

// k_T: grid (JS, 128), 256 threads. Tpart[jc][i][h] partial over j-chunk.
// Also emits rowsum partials rspart[jc][i] from the staged adj tile.
__global__ __launch_bounds__(256) void k_T(const float* __restrict__ pa,
                                           const float* __restrict__ pb,
                                           const float* __restrict__ b1,
                                           const float* __restrict__ adj,
                                           float* __restrict__ Tpart,
                                           float* __restrict__ rspart) {
    __shared__ float adj_s[4 * JCH];
    const int jc = blockIdx.x;
    const int i0 = blockIdx.y * 4;
    const int t = threadIdx.x;
    {
        int idx = t;
        adj_s[idx] = adj[(i0 + (idx >> 7)) * NN + jc * JCH + (idx & 127)];
        idx = t + 256;
        adj_s[idx] = adj[(i0 + (idx >> 7)) * NN + jc * JCH + (idx & 127)];
    }
    const int h = t;
    const float bb = b1[h];
    float pbh[4];
    float acc[4] = {0.f, 0.f, 0.f, 0.f};
    #pragma unroll
    for (int ti = 0; ti < 4; ++ti) pbh[ti] = pb[(i0 + ti) * HH + h] + bb;
    __syncthreads();
    const float* pac = pa + (jc * JCH) * HH + h;
    for (int jj = 0; jj < JCH; jj += 4) {
        float p0 = pac[(jj + 0) * HH];
        float p1 = pac[(jj + 1) * HH];
        float p2 = pac[(jj + 2) * HH];
        float p3 = pac[(jj + 3) * HH];
        #pragma unroll
        for (int ti = 0; ti < 4; ++ti) {
            float4 a = *(const float4*)&adj_s[ti * JCH + jj];
            acc[ti] += a.x * fmaxf(p0 + pbh[ti], 0.f);
            acc[ti] += a.y * fmaxf(p1 + pbh[ti], 0.f);
            acc[ti] += a.z * fmaxf(p2 + pbh[ti], 0.f);
            acc[ti] += a.w * fmaxf(p3 + pbh[ti], 0.f);
        }
    }
    float* Tp = Tpart + jc * (NN * HH);
    #pragma unroll
    for (int ti = 0; ti < 4; ++ti) Tp[(i0 + ti) * HH + h] = acc[ti];
    // rowsum partials: wave w reduces adj_s[w][0..127]
    {
        const int w = t >> 6;
        const int l = t & 63;
        float v = adj_s[w * JCH + l] + adj_s[w * JCH + l + 64];
        #pragma unroll
        for (int off = 32; off > 0; off >>= 1) v += __shfl_down(v, off, 64);
        if (l == 0) rspart[jc * NN + i0 + w] = v;
    }
}

__device__ __forceinline__ float stage_dot(const float* __restrict__ W,
                                           const float* srcRow, int k) {
    const float4* w4 = (const float4*)(W + k * HH);
    const float4* a4 = (const float4*)srcRow;
    float c0 = 0.f, c1 = 0.f, c2 = 0.f, c3 = 0.f;
    #pragma unroll 4
    for (int h4 = 0; h4 < HH / 4; h4 += 4) {
        c0 += dot4(w4[h4 + 0], a4[h4 + 0]);
        c1 += dot4(w4[h4 + 1], a4[h4 + 1]);
        c2 += dot4(w4[h4 + 2], a4[h4 + 2]);
        c3 += dot4(w4[h4 + 3], a4[h4 + 3]);
    }
    return (c0 + c1) + (c2 + c3);
}

// k_out: 128 blocks x 1024 threads (16 waves -> 4 waves/SIMD).
// thread: r = t>>8 (row in tile), k = t&255 (output col).
__global__ __launch_bounds__(1024) void k_out(const float* __restrict__ Tpart,
                                              const float* __restrict__ rspart,
                                              const float* __restrict__ W2,
                                              const float* __restrict__ b2,
                                              const float* __restrict__ Wo1,
                                              const float* __restrict__ bo1,
                                              const float* __restrict__ Wo2,
                                              const float* __restrict__ bo2,
                                              float* __restrict__ out) {
    __shared__ float bufA[4][HH];
    __shared__ float bufB[4][HH];
    const int t = threadIdx.x;
    const int r = t >> 8;
    const int k = t & 255;
    const int i0 = blockIdx.x * 4;
    // prologue: reduce Tpart partials + rowsum partials
    {
        float s = 0.f;
        #pragma unroll
        for (int jc = 0; jc < JS; ++jc)
            s += Tpart[jc * (NN * HH) + (i0 + r) * HH + k];
        bufA[r][k] = s;
    }
    float rsum = 0.f;
    #pragma unroll
    for (int jc = 0; jc < JS; ++jc) rsum += rspart[jc * NN + i0 + r];
    __syncthreads();
    // stage 1: pred -> bufB
    {
        float d = stage_dot(W2, &bufA[r][0], k);
        bufB[r][k] = (d + b2[k] * rsum) * (1.0f / (float)NN);
    }
    __syncthreads();
    // stage 2: h2 = relu(pred @ Wo1^T + bo1) -> bufA
    {
        float d = stage_dot(Wo1, &bufB[r][0], k);
        bufA[r][k] = fmaxf(d + bo1[k], 0.f);
    }
    __syncthreads();
    // stage 3: out = h2 @ Wo2^T + bo2
    {
        float d = stage_dot(Wo2, &bufA[r][0], k);
        out[(i0 + r) * OO + k] = d + bo2[k];
    }
}

extern "C" void kernel_launch(void* const* d_in, const int* in_sizes, int n_in,
                              void* d_out, int out_size, void* d_ws, size_t ws_size,
                              hipStream_t stream) {
    const float* x   = (const float*)d_in[0];
    const float* adj = (const float*)d_in[1];
    const float* W1  = (const float*)d_in[2];
    const float* b1  = (const float*)d_in[3];
    const float* W2  = (const float*)d_in[4];
    const float* b2  = (const float*)d_in[5];
    const float* Wo1 = (const float*)d_in[6];
    const float* bo1 = (const float*)d_in[7];
    const float* Wo2 = (const float*)d_in[8];
    const float* bo2 = (const float*)d_in[9];
    float* out = (float*)d_out;

    float* ws = (float*)d_ws;
    float* pa     = ws;                    // 512*256
    float* pb     = ws + 131072;           // 512*256
    float* rspart = ws + 262144;           // JS*512
    float* Tpart  = ws + 264192;           // JS*512*256

    k_papb<<<dim3(NN / 4, 2), 256, 0, stream>>>(x, W1, pa, pb);
    k_T<<<dim3(JS, NN / 4), 256, 0, stream>>>(pa, pb, b1, adj, Tpart, rspart);
    k_out<<<NN / 4, 1024, 0, stream>>>(Tpart, rspart, W2, b2, Wo1, bo1, Wo2, bo2, out);
}

// Round 3
// 46.888 us; speedup vs baseline: 2.4473x; 2.4473x over previous
//
#include <hip/hip_runtime.h>

#define NN 512
#define DD 128
#define HH 256
#define OO 256

__device__ __forceinline__ float dot4(float4 a, float4 b) {
    return a.x * b.x + a.y * b.y + a.z * b.z + a.w * b.w;
}

// ---------------------------------------------------------------------------
// k_pre: blocks 0..255  -> pa/pbb (pb + b1 prefused), rows=2 per block
//        blocks 256..303 -> transpose W2, Wo1, Wo2 into ws (WT[h][k] = W[k][h])
// ---------------------------------------------------------------------------
__global__ __launch_bounds__(256) void k_pre(const float* __restrict__ x,
                                             const float* __restrict__ W1,
                                             const float* __restrict__ b1,
                                             const float* __restrict__ W2,
                                             const float* __restrict__ Wo1,
                                             const float* __restrict__ Wo2,
                                             float* __restrict__ pa,
                                             float* __restrict__ pbb,
                                             float* __restrict__ wsT) {
    __shared__ float tlds[64][68];
    __shared__ float xs[2][DD];
    const int t = threadIdx.x;
    const int b = blockIdx.x;
    if (b < 256) {
        const int i0 = b * 2;
        xs[t >> 7][t & 127] = x[i0 * DD + t];
        __syncthreads();
        const int h = t;
        const float4* wa = (const float4*)(W1 + h * (2 * DD));
        const float4* wb = wa + (DD / 4);
        float a0 = 0.f, a1 = 0.f, c0 = 0.f, c1 = 0.f;
        #pragma unroll 4
        for (int d4 = 0; d4 < DD / 4; ++d4) {
            float4 WA = wa[d4];
            float4 WB = wb[d4];
            float4 X0 = *(const float4*)&xs[0][d4 * 4];
            float4 X1 = *(const float4*)&xs[1][d4 * 4];
            a0 += dot4(WA, X0);
            a1 += dot4(WA, X1);
            c0 += dot4(WB, X0);
            c1 += dot4(WB, X1);
        }
        const float bb = b1[h];
        pa[i0 * HH + h] = a0;
        pa[(i0 + 1) * HH + h] = a1;
        pbb[i0 * HH + h] = c0 + bb;
        pbb[(i0 + 1) * HH + h] = c1 + bb;
    } else {
        const int bb = b - 256;
        const int m = bb >> 4;
        const int tile = bb & 15;
        const float* W = (m == 0) ? W2 : (m == 1) ? Wo1 : Wo2;
        float* WT = wsT + m * (HH * HH);
        const int k0 = (tile >> 2) * 64;
        const int h0 = (tile & 3) * 64;
        const int rr = t >> 4;
        const int cc = (t & 15) * 4;
        #pragma unroll
        for (int it = 0; it < 4; ++it) {
            float4 v = *(const float4*)&W[(k0 + rr + 16 * it) * HH + h0 + cc];
            tlds[rr + 16 * it][cc + 0] = v.x;
            tlds[rr + 16 * it][cc + 1] = v.y;
            tlds[rr + 16 * it][cc + 2] = v.z;
            tlds[rr + 16 * it][cc + 3] = v.w;
        }
        __syncthreads();
        #pragma unroll
        for (int it = 0; it < 4; ++it) {
            const int hl = rr + 16 * it;
            float4 o;
            o.x = tlds[cc + 0][hl];
            o.y = tlds[cc + 1][hl];
            o.z = tlds[cc + 2][hl];
            o.w = tlds[cc + 3][hl];
            *(float4*)&WT[(h0 + hl) * HH + k0 + cc] = o;
        }
    }
}

// ---------------------------------------------------------------------------
// k_T: grid (2 h-halves, 128 i-tiles), 512 threads = 4 j-quarters x 128 h.
// Writes final Tsum[i][h] and rowsum[i].
// ---------------------------------------------------------------------------
#define ADJP 516
__global__ __launch_bounds__(512) void k_T(const float* __restrict__ pa,
                                           const float* __restrict__ pbb,
                                           const float* __restrict__ adj,
                                           float* __restrict__ Tsum,
                                           float* __restrict__ rowsum) {
    __shared__ float adj_s[4 * ADJP];
    __shared__ float red[3][4][128];
    const int t = threadIdx.x;
    const int hb = blockIdx.x;
    const int i0 = blockIdx.y * 4;
    {
        const int f = t * 4;
        const int r = f >> 9;
        const int c = f & 511;
        *(float4*)&adj_s[r * ADJP + c] = *(const float4*)&adj[(i0 + r) * NN + c];
    }
    const int jh = t >> 7;
    const int hl = t & 127;
    const int h = hb * 128 + hl;
    float pbv[4], acc[4] = {0.f, 0.f, 0.f, 0.f};
    #pragma unroll
    for (int r = 0; r < 4; ++r) pbv[r] = pbb[(i0 + r) * HH + h];
    __syncthreads();
    const float* pac = pa + (jh * 128) * HH + h;
    const int jb = jh * 128;
    #pragma unroll 4
    for (int j4 = 0; j4 < 32; ++j4) {
        const int j = j4 * 4;
        float p0 = pac[(j + 0) * HH];
        float p1 = pac[(j + 1) * HH];
        float p2 = pac[(j + 2) * HH];
        float p3 = pac[(j + 3) * HH];
        #pragma unroll
        for (int r = 0; r < 4; ++r) {
            float4 a = *(const float4*)&adj_s[r * ADJP + jb + j];
            acc[r] += a.x * fmaxf(p0 + pbv[r], 0.f);
            acc[r] += a.y * fmaxf(p1 + pbv[r], 0.f);
            acc[r] += a.z * fmaxf(p2 + pbv[r], 0.f);
            acc[r] += a.w * fmaxf(p3 + pbv[r], 0.f);
        }
    }
    if (jh >= 1) {
        #pragma unroll
        for (int r = 0; r < 4; ++r) red[jh - 1][r][hl] = acc[r];
    }
    __syncthreads();
    if (jh == 0) {
        #pragma unroll
        for (int r = 0; r < 4; ++r) {
            float s = acc[r] + red[0][r][hl] + red[1][r][hl] + red[2][r][hl];
            Tsum[(i0 + r) * HH + h] = s;
        }
    }
    if (hb == 0 && t < 256) {
        const int r = t >> 6;
        const int l = t & 63;
        float s = 0.f;
        #pragma unroll
        for (int m = 0; m < 8; ++m) s += adj_s[r * ADJP + l + 64 * m];
        #pragma unroll
        for (int off = 32; off > 0; off >>= 1) s += __shfl_down(s, off, 64);
        if (l == 0) rowsum[i0 + r] = s;
    }
}

// ---------------------------------------------------------------------------
// k_stage<MODE>: C[512x256] = A[512x256] @ WT (coalesced), grid (4 colblk, 128
// rowtiles), 256 thr = 4 h-phases x (4 rows x 16 colquads), LDS h-reduce.
// MODE 0: pred = (acc + b2[k]*rowsum[i]) / N
// MODE 1: h2   = relu(acc + bias)
// MODE 2: out  = acc + bias
// ---------------------------------------------------------------------------
#define ASP (HH + 4)
template <int MODE>
__global__ __launch_bounds__(256) void k_stage(const float* __restrict__ A,
                                               const float* __restrict__ WT,
                                               const float* __restrict__ bias,
                                               const float* __restrict__ rowsum,
                                               float* __restrict__ out) {
    __shared__ float As[4 * ASP];
    __shared__ float red[4][4][64];
    const int t = threadIdx.x;
    const int i0 = blockIdx.y * 4;
    const int k0 = blockIdx.x * 64;
    {
        const int f = t * 4;
        const int r = f >> 8;
        const int c = f & 255;
        *(float4*)&As[r * ASP + c] = *(const float4*)&A[(i0 + r) * HH + c];
    }
    __syncthreads();
    const int ph = t >> 6;
    const int lane = t & 63;
    const int r = lane >> 4;
    const int cq = lane & 15;
    const float* wt = WT + k0 + cq * 4;
    const float* as = &As[r * ASP + ph * 64];
    float4 acc = {0.f, 0.f, 0.f, 0.f};
    #pragma unroll 2
    for (int hh = 0; hh < 64; hh += 4) {
        float4 av = *(const float4*)&as[hh];
        float4 w0 = *(const float4*)&wt[(ph * 64 + hh + 0) * HH];
        float4 w1 = *(const float4*)&wt[(ph * 64 + hh + 1) * HH];
        float4 w2 = *(const float4*)&wt[(ph * 64 + hh + 2) * HH];
        float4 w3 = *(const float4*)&wt[(ph * 64 + hh + 3) * HH];
        acc.x += av.x * w0.x + av.y * w1.x + av.z * w2.x + av.w * w3.x;
        acc.y += av.x * w0.y + av.y * w1.y + av.z * w2.y + av.w * w3.y;
        acc.z += av.x * w0.z + av.y * w1.z + av.z * w2.z + av.w * w3.z;
        acc.w += av.x * w0.w + av.y * w1.w + av.z * w2.w + av.w * w3.w;
    }
    *(float4*)&red[ph][r][cq * 4] = acc;
    __syncthreads();
    if (ph == 0) {
        float4 s = acc;
        #pragma unroll
        for (int p = 1; p < 4; ++p) {
            float4 o = *(const float4*)&red[p][r][cq * 4];
            s.x += o.x; s.y += o.y; s.z += o.z; s.w += o.w;
        }
        const int k = k0 + cq * 4;
        float4 bv = *(const float4*)&bias[k];
        if (MODE == 0) {
            const float rs = rowsum[i0 + r];
            const float inv = 1.0f / (float)NN;
            s.x = (s.x + bv.x * rs) * inv;
            s.y = (s.y + bv.y * rs) * inv;
            s.z = (s.z + bv.z * rs) * inv;
            s.w = (s.w + bv.w * rs) * inv;
        } else if (MODE == 1) {
            s.x = fmaxf(s.x + bv.x, 0.f);
            s.y = fmaxf(s.y + bv.y, 0.f);
            s.z = fmaxf(s.z + bv.z, 0.f);
            s.w = fmaxf(s.w + bv.w, 0.f);
        } else {
            s.x += bv.x; s.y += bv.y; s.z += bv.z; s.w += bv.w;
        }
        *(float4*)&out[(i0 + r) * HH + k] = s;
    }
}

extern "C" void kernel_launch(void* const* d_in, const int* in_sizes, int n_in,
                              void* d_out, int out_size, void* d_ws, size_t ws_size,
                              hipStream_t stream) {
    const float* x   = (const float*)d_in[0];
    const float* adj = (const float*)d_in[1];
    const float* W1  = (const float*)d_in[2];
    const float* b1  = (const float*)d_in[3];
    const float* W2  = (const float*)d_in[4];
    const float* b2  = (const float*)d_in[5];
    const float* Wo1 = (const float*)d_in[6];
    const float* bo1 = (const float*)d_in[7];
    const float* Wo2 = (const float*)d_in[8];
    const float* bo2 = (const float*)d_in[9];
    float* out = (float*)d_out;

    float* ws = (float*)d_ws;
    float* pa     = ws;            // 131072
    float* pbb    = ws + 131072;   // 131072
    float* wsT    = ws + 262144;   // 3 * 65536 (W2T, Wo1T, Wo2T)
    float* W2T    = wsT;
    float* Wo1T   = wsT + 65536;
    float* Wo2T   = wsT + 131072;
    float* Tsum   = ws + 458752;   // 131072
    float* rowsum = ws + 589824;   // 512
    float* pred   = ws + 590336;   // 131072
    float* h2     = ws + 721408;   // 131072

    k_pre<<<304, 256, 0, stream>>>(x, W1, b1, W2, Wo1, Wo2, pa, pbb, wsT);
    k_T<<<dim3(2, 128), 512, 0, stream>>>(pa, pbb, adj, Tsum, rowsum);
    k_stage<0><<<dim3(4, 128), 256, 0, stream>>>(Tsum, W2T, b2, rowsum, pred);
    k_stage<1><<<dim3(4, 128), 256, 0, stream>>>(pred, Wo1T, bo1, rowsum, h2);
    k_stage<2><<<dim3(4, 128), 256, 0, stream>>>(h2, Wo2T, bo2, rowsum, out);
}